// Round 16
// baseline (61.869 us; speedup 1.0000x reference)
//
#include <hip/hip_runtime.h>
#include <hip/hip_bf16.h>
#include <math.h>
#include <string.h>

#define NB 8
#define NC 256
#define HWSZ 1024
#define NHEAD 8
#define DHEAD 32
#define NGRP 32
#define CPG 8
#define EPSV 1e-5f

typedef float f32x4 __attribute__((ext_vector_type(4)));
typedef short bf16x8 __attribute__((ext_vector_type(8)));

__device__ __forceinline__ unsigned pk2(float a, float b) {
    __hip_bfloat162 h = __float22bfloat162_rn(make_float2(a, b));
    unsigned r;
    memcpy(&r, &h, sizeof(r));
    return r;
}
// truncation pack (RTZ): P >= 0, rel error <= 0.4% downward
__device__ __forceinline__ unsigned pk2t(float a, float b) {
    unsigned ua = __float_as_uint(a), ub = __float_as_uint(b);
    return (ua >> 16) | (ub & 0xFFFF0000u);
}
__device__ __forceinline__ unsigned short f2bf(float x) {
    __hip_bfloat16 h = __float2bfloat16(x);
    unsigned short r;
    memcpy(&r, &h, sizeof(r));
    return r;
}
__device__ __forceinline__ float ex2(float x) { return __builtin_amdgcn_exp2f(x); }

// async global->LDS, 16B per lane; LDS dest = wave-uniform base + lane*16
__device__ __forceinline__ void gload_lds16(const void* g, void* l) {
    __builtin_amdgcn_global_load_lds(
        (const __attribute__((address_space(1))) unsigned int*)g,
        (__attribute__((address_space(3))) unsigned int*)l, 16, 0, 0);
}

// ---------------- prep: GroupNorm stats (blocks 0..511) + weight bf16 convert (512..639) ----
__global__ void prep_kernel(const float* __restrict__ xq,
                            const float* __restrict__ xkv,
                            float* __restrict__ stats,
                            const float* __restrict__ Wq,
                            const float* __restrict__ Wkv,
                            const float* __restrict__ Wout,
                            unsigned short* __restrict__ wqb,
                            unsigned short* __restrict__ wkvb,
                            unsigned short* __restrict__ woutb) {
    if (blockIdx.x < 512) {
        int idx = blockIdx.x;            // which*256 + b*32 + g
        int which = idx >> 8;
        int b = (idx >> 5) & 7;
        int g = idx & 31;
        const float* x = which ? xkv : xq;
        const float4* xb = (const float4*)(x + ((size_t)(b * NC + g * CPG)) * HWSZ);
        float s = 0.f, ss = 0.f;
        for (int i = threadIdx.x; i < (CPG * HWSZ) / 4; i += 256) {
            float4 v = xb[i];
            s += v.x + v.y + v.z + v.w;
            ss += v.x * v.x + v.y * v.y + v.z * v.z + v.w * v.w;
        }
        #pragma unroll
        for (int off = 32; off > 0; off >>= 1) {
            s += __shfl_down(s, off);
            ss += __shfl_down(ss, off);
        }
        __shared__ float red[8];
        int wid = threadIdx.x >> 6;
        if ((threadIdx.x & 63) == 0) { red[wid * 2] = s; red[wid * 2 + 1] = ss; }
        __syncthreads();
        if (threadIdx.x == 0) {
            float S = red[0] + red[2] + red[4] + red[6];
            float SS = red[1] + red[3] + red[5] + red[7];
            float mean = S * (1.f / (CPG * HWSZ));
            float var = SS * (1.f / (CPG * HWSZ)) - mean * mean;
            stats[idx * 2] = mean;
            stats[idx * 2 + 1] = rsqrtf(var + EPSV);
        }
    } else {
        int gid = (blockIdx.x - 512) * 256 + threadIdx.x;   // 32768 threads, 8 floats
        int i0 = gid * 8;
        const float* src; unsigned short* dst; int off; float sc = 1.f;
        if (i0 < 65536)       { src = Wq;   dst = wqb;   off = i0;          sc = 0.0625f * 1.44269504088896f; }
        else if (i0 < 196608) { src = Wkv;  dst = wkvb;  off = i0 - 65536; }
        else                  { src = Wout; dst = woutb; off = i0 - 196608; }
        float4 v0 = *(const float4*)&src[off];
        float4 v1 = *(const float4*)&src[off + 4];
        uint4 o;
        o.x = pk2(v0.x * sc, v0.y * sc); o.y = pk2(v0.z * sc, v0.w * sc);
        o.z = pk2(v1.x * sc, v1.y * sc); o.w = pk2(v1.z * sc, v1.w * sc);
        *(uint4*)&dst[off] = o;
    }
}

// ---------------- fused QKV GEMM: X read ONCE per block ----------------
// Block = (16-p-slice, b), grid (64, 8). Stage normalized bf16 tiles of BOTH
// inputs (16p x 256c each, XOR-swizzled), then loop 12 weight tiles with A
// read directly from global (weights L2-hot, no per-tile barrier -> loads
// hoistable). X traffic: 100 MB -> 16.8 MB; norm computed once, not 4-8x.
__global__ __launch_bounds__(256) void qkv_gemm_kernel(
        const unsigned short* __restrict__ wqb,
        const unsigned short* __restrict__ wkvb,
        const float* __restrict__ xq, const float* __restrict__ xkv,
        const float* __restrict__ stats,
        const float* __restrict__ sq, const float* __restrict__ bq,
        const float* __restrict__ skv, const float* __restrict__ bkv,
        unsigned short* __restrict__ qbuf,
        unsigned short* __restrict__ kbuf,
        unsigned short* __restrict__ vbuf) {
    __shared__ unsigned short BqS[16 * 256];
    __shared__ unsigned short BkvS[16 * 256];
    const int tid = threadIdx.x;
    const int l16 = tid & 15, g = (tid >> 4) & 3, w = tid >> 6;
    const int b = blockIdx.y;
    const int pp = blockIdx.x * 16;

    // ---- stage both inputs: norm + bf16 + 4x4 reg transpose -> swizzled LDS
    const int cq = tid & 63, pq = tid >> 6;   // c-quad (0..63), p-quad (0..3)
    const int cb = cq * 4;
    #pragma unroll
    for (int which = 0; which < 2; ++which) {
        const float* X  = (which ? xkv : xq) + (size_t)b * NC * HWSZ + pp;
        const float* st = stats + which * 512 + b * 64;
        const float* sc = which ? skv : sq;
        const float* bi = which ? bkv : bq;
        unsigned short* Bs = which ? BkvS : BqS;
        int grp = cb >> 3;
        float mean = st[grp * 2], rstd = st[grp * 2 + 1];
        float mm[4][4];
        #pragma unroll
        for (int u = 0; u < 4; ++u) {
            int c = cb + u;
            float4 v = *(const float4*)&X[(size_t)c * HWSZ + pq * 4];
            float a = rstd * sc[c];
            float bbv = bi[c] - mean * a;
            mm[u][0] = v.x * a + bbv; mm[u][1] = v.y * a + bbv;
            mm[u][2] = v.z * a + bbv; mm[u][3] = v.w * a + bbv;
        }
        #pragma unroll
        for (int v2 = 0; v2 < 4; ++v2) {
            int row = pq * 4 + v2;
            int ds = row * 256 + ((((cb >> 3) ^ (row & 7))) << 3) + (cb & 7);
            uint2 s2;
            s2.x = pk2(mm[0][v2], mm[1][v2]);
            s2.y = pk2(mm[2][v2], mm[3][v2]);
            *(uint2*)&Bs[ds] = s2;
        }
    }
    __syncthreads();

    const int asw = l16 & 7;
    const int arow = (16 * w + l16) * NC;   // A row offset within a 64-o tile
    #pragma unroll
    for (int y2 = 0; y2 < 12; ++y2) {
        const bool isQ = y2 < 4;
        const int o0 = (isQ ? y2 : y2 - 4) * 64;
        const unsigned short* Asrc = (isQ ? wqb : wkvb) + (size_t)o0 * NC + arow;
        const unsigned short* Bs = isQ ? BqS : BkvS;
        f32x4 acc = {0.f, 0.f, 0.f, 0.f};
        #pragma unroll
        for (int kk = 0; kk < 8; ++kk) {
            bf16x8 a = *(const bf16x8*)&Asrc[(kk * 4 + g) << 3];
            bf16x8 bfr = *(const bf16x8*)&Bs[l16 * 256 + (((kk * 4 + g) ^ asw) << 3)];
            acc = __builtin_amdgcn_mfma_f32_16x16x32_bf16(a, bfr, acc, 0, 0, 0);
        }
        int ob_ = o0 + 16 * w + 4 * g;
        if (isQ) {
            int n = ob_ >> 5, d0 = ob_ & 31;
            int p = pp + l16;
            unsigned short* dst = qbuf + (((size_t)(b * NHEAD + n) * HWSZ) + p) * DHEAD + d0;
            uint2 st2;
            st2.x = pk2(acc[0], acc[1]);
            st2.y = pk2(acc[2], acc[3]);
            *(uint2*)dst = st2;
        } else {
            int n = y2 - 4;
            int d0 = 16 * (w & 1) + 4 * g;
            if (w < 2) {   // K rows (0..31 of the weight tile)
                int p = pp + l16;
                unsigned short* dst = kbuf + (((size_t)(b * NHEAD + n) * HWSZ) + p) * DHEAD + d0;
                uint2 st2;
                st2.x = pk2(acc[0], acc[1]);
                st2.y = pk2(acc[2], acc[3]);
                *(uint2*)dst = st2;
            } else {       // V rows (32..63) -> [b][n][d][p'] sigma-permuted
                int sel = (pp >> 4) & 1;
                int p32 = pp & ~31;
                int slot = ((l16 >> 2) << 3) + (sel << 2) + (l16 & 3);
                int p = p32 + slot;
                unsigned short* dst = vbuf + ((size_t)(b * NHEAD + n) * DHEAD + d0) * HWSZ;
                #pragma unroll
                for (int r = 0; r < 4; ++r)
                    dst[(size_t)r * HWSZ + p] = f2bf(acc[r]);
            }
        }
    }
}

// ---------------- out GEMM: obuf(A, rows p) x Wout(B, rows o) + bias + residual ----
__global__ __launch_bounds__(256) void out_gemm_kernel(
        const unsigned short* __restrict__ Abase,
        const unsigned short* __restrict__ Bbase,
        const float* __restrict__ bias_out,
        const float* __restrict__ resid,
        float* __restrict__ out0) {
    __shared__ unsigned short As[64 * 256];
    __shared__ unsigned short Bs[64 * 256];
    const int tid = threadIdx.x;
    const int l16 = tid & 15, g = (tid >> 4) & 3, w = tid >> 6;
    const int o0 = blockIdx.y * 64;
    const size_t prow0 = (size_t)blockIdx.x * 64;
    const unsigned short* Asrc = Abase + prow0 * NC;
    const unsigned short* Bsrc = Bbase + (size_t)o0 * NC;
    #pragma unroll
    for (int it = 0; it < 8; ++it) {
        int idx = tid + it * 256;
        int row = idx >> 5, seg = idx & 31;
        int ds = row * 256 + ((seg ^ (row & 7)) << 3);
        *(uint4*)&As[ds] = *(const uint4*)&Asrc[(size_t)row * NC + seg * 8];
        *(uint4*)&Bs[ds] = *(const uint4*)&Bsrc[(size_t)row * NC + seg * 8];
    }
    __syncthreads();
    f32x4 acc[4] = {};
    const int abase = (w * 16 + l16) * 256;
    const int asw = l16 & 7;
    #pragma unroll
    for (int kk = 0; kk < 8; ++kk) {
        const int koff = ((kk * 4 + g) ^ asw) << 3;
        bf16x8 a = *(const bf16x8*)&As[abase + koff];
        #pragma unroll
        for (int j = 0; j < 4; ++j) {
            bf16x8 b = *(const bf16x8*)&Bs[(j * 16 + l16) * 256 + koff];
            acc[j] = __builtin_amdgcn_mfma_f32_16x16x32_bf16(a, b, acc[j], 0, 0, 0);
        }
    }
    const int b = (int)(prow0 >> 10);
    const int pp = (int)(prow0 & 1023);
    int p_b = pp + 16 * w + 4 * g;
    #pragma unroll
    for (int j = 0; j < 4; ++j) {
        int o = o0 + 16 * j + l16;
        float bo = bias_out[o];
        size_t off = ((size_t)b * NC + o) * HWSZ + p_b;
        float4 rs = *(const float4*)&resid[off];
        float4 vst = make_float4(acc[j][0] + bo + rs.x, acc[j][1] + bo + rs.y,
                                 acc[j][2] + bo + rs.z, acc[j][3] + bo + rs.w);
        *(float4*)&out0[off] = vst;
    }
}

// ---------------- MFMA flash attention: async-LDS staging, max-free softmax ----
// (round-15 winner, unchanged)
__global__ __launch_bounds__(256) void attn_mfma_kernel(
        const unsigned short* __restrict__ qb,
        const unsigned short* __restrict__ kb,
        const unsigned short* __restrict__ vb,
        unsigned short* __restrict__ ob) {
    __shared__ unsigned short KV[3][4096];   // [buf][K: 0..2047 | V: 2048..4095]
    const int tid = threadIdx.x;
    const int w = tid >> 6, lane = tid & 63;
    const int l16 = lane & 15, g = lane >> 4;
    const int F = blockIdx.y * 16 + blockIdx.x;
    const int bn = (F & 7) * 8 + (F >> 7);
    const int qblk = (F >> 3) & 15;
    const int qp = qblk * 64 + w * 16 + l16;

    bf16x8 qf = *(const bf16x8*)(qb + ((size_t)bn * HWSZ + qp) * DHEAD + g * 8);

    const int kr = tid >> 2, ks = tid & 3;
    const unsigned short* ksrc = kb + (size_t)bn * HWSZ * DHEAD
                               + (size_t)kr * DHEAD + ((ks ^ (kr & 3)) << 3);
    const int vr = tid >> 3, vs = tid & 7;
    const unsigned short* vsrc = vb + (size_t)bn * DHEAD * HWSZ
                               + (size_t)vr * HWSZ + ((vs ^ (vr & 7)) << 3);
    unsigned short* lk = &KV[0][0] + w * 512;
    unsigned short* lv = &KV[0][2048] + w * 512;

#define STAGE(t) do {                                                        \
        int b3_ = (t) % 3; int ti_ = (t) & 15;                               \
        gload_lds16(ksrc + (size_t)ti_ * 64 * DHEAD, lk + b3_ * 4096);       \
        gload_lds16(vsrc + (size_t)ti_ * 64,         lv + b3_ * 4096);       \
    } while (0)

    f32x4 acc0 = {0.f, 0.f, 0.f, 0.f}, acc1 = {0.f, 0.f, 0.f, 0.f};
    f32x4 accl = {0.f, 0.f, 0.f, 0.f};
    const f32x4 z = {0.f, 0.f, 0.f, 0.f};

    const unsigned on2 = 0x3F803F80u;    // two bf16 1.0
    uint4 onev = make_uint4(on2, on2, on2, on2);
    bf16x8 ones;
    memcpy(&ones, &onev, sizeof(ones));

    const int ksw  = (g ^ (l16 & 3)) << 3;
    const int vsw0 = ((g)     ^ (l16 & 7)) << 3;
    const int vsw1 = ((4 + g) ^ (l16 & 7)) << 3;

    STAGE(0);
    STAGE(1);

    #pragma unroll
    for (int t = 0; t < 16; ++t) {
        const int cur = t % 3;
        asm volatile("s_waitcnt vmcnt(2)" ::: "memory");
        __builtin_amdgcn_s_barrier();
        STAGE(t + 2);

        const unsigned short* Kb = &KV[cur][0];
        const unsigned short* Vb = &KV[cur][2048];
        bf16x8 ka0 = *(const bf16x8*)&Kb[(l16)      * 32 + ksw];
        bf16x8 ka1 = *(const bf16x8*)&Kb[(16 + l16) * 32 + ksw];
        bf16x8 ka2 = *(const bf16x8*)&Kb[(32 + l16) * 32 + ksw];
        bf16x8 ka3 = *(const bf16x8*)&Kb[(48 + l16) * 32 + ksw];

        __builtin_amdgcn_s_setprio(1);
        f32x4 s0 = __builtin_amdgcn_mfma_f32_16x16x32_bf16(ka0, qf, z, 0, 0, 0);
        f32x4 s1 = __builtin_amdgcn_mfma_f32_16x16x32_bf16(ka1, qf, z, 0, 0, 0);
        f32x4 s2 = __builtin_amdgcn_mfma_f32_16x16x32_bf16(ka2, qf, z, 0, 0, 0);
        f32x4 s3 = __builtin_amdgcn_mfma_f32_16x16x32_bf16(ka3, qf, z, 0, 0, 0);
        __builtin_amdgcn_s_setprio(0);

        float p00 = ex2(s0[0]), p01 = ex2(s0[1]);
        float p02 = ex2(s0[2]), p03 = ex2(s0[3]);
        float p10 = ex2(s1[0]), p11 = ex2(s1[1]);
        float p12 = ex2(s1[2]), p13 = ex2(s1[3]);
        float p20 = ex2(s2[0]), p21 = ex2(s2[1]);
        float p22 = ex2(s2[2]), p23 = ex2(s2[3]);
        float p30 = ex2(s3[0]), p31 = ex2(s3[1]);
        float p32 = ex2(s3[2]), p33 = ex2(s3[3]);

        uint4 pwa, pwb;
        pwa.x = pk2t(p00, p01); pwa.y = pk2t(p02, p03);
        pwa.z = pk2t(p10, p11); pwa.w = pk2t(p12, p13);
        pwb.x = pk2t(p20, p21); pwb.y = pk2t(p22, p23);
        pwb.z = pk2t(p30, p31); pwb.w = pk2t(p32, p33);
        bf16x8 pf0, pf1;
        memcpy(&pf0, &pwa, sizeof(pf0));
        memcpy(&pf1, &pwb, sizeof(pf1));

        bf16x8 va0 = *(const bf16x8*)&Vb[(l16)      * 64 + vsw0];
        bf16x8 va1 = *(const bf16x8*)&Vb[(l16)      * 64 + vsw1];
        bf16x8 vb0 = *(const bf16x8*)&Vb[(16 + l16) * 64 + vsw0];
        bf16x8 vb1 = *(const bf16x8*)&Vb[(16 + l16) * 64 + vsw1];

        __builtin_amdgcn_s_setprio(1);
        acc0 = __builtin_amdgcn_mfma_f32_16x16x32_bf16(va0, pf0, acc0, 0, 0, 0);
        acc0 = __builtin_amdgcn_mfma_f32_16x16x32_bf16(va1, pf1, acc0, 0, 0, 0);
        acc1 = __builtin_amdgcn_mfma_f32_16x16x32_bf16(vb0, pf0, acc1, 0, 0, 0);
        acc1 = __builtin_amdgcn_mfma_f32_16x16x32_bf16(vb1, pf1, acc1, 0, 0, 0);
        accl = __builtin_amdgcn_mfma_f32_16x16x32_bf16(ones, pf0, accl, 0, 0, 0);
        accl = __builtin_amdgcn_mfma_f32_16x16x32_bf16(ones, pf1, accl, 0, 0, 0);
        __builtin_amdgcn_s_setprio(0);
    }
#undef STAGE

    float invl = 1.f / accl[0];

    const int b = bn >> 3, n = bn & 7;
    unsigned short* dst = ob + ((size_t)b * HWSZ + qp) * NC + n * DHEAD;
    uint2 st0, st1;
    st0.x = pk2(acc0[0] * invl, acc0[1] * invl);
    st0.y = pk2(acc0[2] * invl, acc0[3] * invl);
    st1.x = pk2(acc1[0] * invl, acc1[1] * invl);
    st1.y = pk2(acc1[2] * invl, acc1[3] * invl);
    *(uint2*)&dst[4 * g]      = st0;
    *(uint2*)&dst[16 + 4 * g] = st1;
}

extern "C" void kernel_launch(void* const* d_in, const int* in_sizes, int n_in,
                              void* d_out, int out_size, void* d_ws, size_t ws_size,
                              hipStream_t stream) {
    const float* input_q  = (const float*)d_in[0];
    const float* input_kv = (const float*)d_in[1];
    const float* gq_scale = (const float*)d_in[2];
    const float* gq_bias  = (const float*)d_in[3];
    const float* gkv_scale = (const float*)d_in[4];
    const float* gkv_bias  = (const float*)d_in[5];
    const float* Wq   = (const float*)d_in[6];
    const float* Wkv  = (const float*)d_in[7];
    const float* Wout = (const float*)d_in[8];
    const float* bout = (const float*)d_in[9];
    float* out = (float*)d_out;

    char* ws = (char*)d_ws;
    float* stats = (float*)ws;                                    // 8 KB
    unsigned short* wqb   = (unsigned short*)(ws + 16384);        // 128 KB
    unsigned short* wkvb  = (unsigned short*)(ws + 16384 + 131072);        // 256 KB
    unsigned short* woutb = (unsigned short*)(ws + 16384 + 131072 + 262144); // 128 KB
    const size_t MB = 1024 * 1024;
    unsigned short* qbuf = (unsigned short*)(ws + 1 * MB);   // 4 MB  [b][n][p][d]
    unsigned short* kbuf = (unsigned short*)(ws + 5 * MB);   // 4 MB  [b][n][p][d]
    unsigned short* vbuf = (unsigned short*)(ws + 9 * MB);   // 4 MB  [b][n][d][p'] sigma-permuted
    unsigned short* obuf = (unsigned short*)(ws + 13 * MB);  // 4 MB  [b][p][c]

    prep_kernel<<<640, 256, 0, stream>>>(input_q, input_kv, stats,
                                         Wq, Wkv, Wout, wqb, wkvb, woutb);
    qkv_gemm_kernel<<<dim3(64, 8), 256, 0, stream>>>(
        wqb, wkvb, input_q, input_kv, stats,
        gq_scale, gq_bias, gkv_scale, gkv_bias, qbuf, kbuf, vbuf);
    attn_mfma_kernel<<<dim3(16, 64), 256, 0, stream>>>(qbuf, kbuf, vbuf, obuf);
    out_gemm_kernel<<<dim3(128, 4), 256, 0, stream>>>(obuf, woutb, bout, input_q, out);
}

// Round 17
// 48.977 us; speedup vs baseline: 1.2632x; 1.2632x over previous
//
#include <hip/hip_runtime.h>
#include <hip/hip_bf16.h>
#include <math.h>
#include <string.h>

#define NB 8
#define NC 256
#define HWSZ 1024
#define NHEAD 8
#define DHEAD 32
#define NGRP 32
#define CPG 8
#define EPSV 1e-5f

typedef float f32x4 __attribute__((ext_vector_type(4)));
typedef short bf16x8 __attribute__((ext_vector_type(8)));

__device__ __forceinline__ unsigned pk2(float a, float b) {
    __hip_bfloat162 h = __float22bfloat162_rn(make_float2(a, b));
    unsigned r;
    memcpy(&r, &h, sizeof(r));
    return r;
}
// truncation pack (RTZ): P >= 0, rel error <= 0.4% downward
__device__ __forceinline__ unsigned pk2t(float a, float b) {
    unsigned ua = __float_as_uint(a), ub = __float_as_uint(b);
    return (ua >> 16) | (ub & 0xFFFF0000u);
}
__device__ __forceinline__ unsigned short f2bf(float x) {
    __hip_bfloat16 h = __float2bfloat16(x);
    unsigned short r;
    memcpy(&r, &h, sizeof(r));
    return r;
}
__device__ __forceinline__ float ex2(float x) { return __builtin_amdgcn_exp2f(x); }

// async global->LDS, 16B per lane; LDS dest = wave-uniform base + lane*16
__device__ __forceinline__ void gload_lds16(const void* g, void* l) {
    __builtin_amdgcn_global_load_lds(
        (const __attribute__((address_space(1))) unsigned int*)g,
        (__attribute__((address_space(3))) unsigned int*)l, 16, 0, 0);
}

// ---------------- prep: GroupNorm stats (blocks 0..511) + weight bf16 convert (512..639) ----
__global__ void prep_kernel(const float* __restrict__ xq,
                            const float* __restrict__ xkv,
                            float* __restrict__ stats,
                            const float* __restrict__ Wq,
                            const float* __restrict__ Wkv,
                            const float* __restrict__ Wout,
                            unsigned short* __restrict__ wqb,
                            unsigned short* __restrict__ wkvb,
                            unsigned short* __restrict__ woutb) {
    if (blockIdx.x < 512) {
        int idx = blockIdx.x;            // which*256 + b*32 + g
        int which = idx >> 8;
        int b = (idx >> 5) & 7;
        int g = idx & 31;
        const float* x = which ? xkv : xq;
        const float4* xb = (const float4*)(x + ((size_t)(b * NC + g * CPG)) * HWSZ);
        float s = 0.f, ss = 0.f;
        for (int i = threadIdx.x; i < (CPG * HWSZ) / 4; i += 256) {
            float4 v = xb[i];
            s += v.x + v.y + v.z + v.w;
            ss += v.x * v.x + v.y * v.y + v.z * v.z + v.w * v.w;
        }
        #pragma unroll
        for (int off = 32; off > 0; off >>= 1) {
            s += __shfl_down(s, off);
            ss += __shfl_down(ss, off);
        }
        __shared__ float red[8];
        int wid = threadIdx.x >> 6;
        if ((threadIdx.x & 63) == 0) { red[wid * 2] = s; red[wid * 2 + 1] = ss; }
        __syncthreads();
        if (threadIdx.x == 0) {
            float S = red[0] + red[2] + red[4] + red[6];
            float SS = red[1] + red[3] + red[5] + red[7];
            float mean = S * (1.f / (CPG * HWSZ));
            float var = SS * (1.f / (CPG * HWSZ)) - mean * mean;
            stats[idx * 2] = mean;
            stats[idx * 2 + 1] = rsqrtf(var + EPSV);
        }
    } else {
        int gid = (blockIdx.x - 512) * 256 + threadIdx.x;   // 32768 threads, 8 floats
        int i0 = gid * 8;
        const float* src; unsigned short* dst; int off; float sc = 1.f;
        if (i0 < 65536)       { src = Wq;   dst = wqb;   off = i0;          sc = 0.0625f * 1.44269504088896f; }
        else if (i0 < 196608) { src = Wkv;  dst = wkvb;  off = i0 - 65536; }
        else                  { src = Wout; dst = woutb; off = i0 - 196608; }
        float4 v0 = *(const float4*)&src[off];
        float4 v1 = *(const float4*)&src[off + 4];
        uint4 o;
        o.x = pk2(v0.x * sc, v0.y * sc); o.y = pk2(v0.z * sc, v0.w * sc);
        o.z = pk2(v1.x * sc, v1.y * sc); o.w = pk2(v1.z * sc, v1.w * sc);
        *(uint4*)&dst[off] = o;
    }
}

// ---------------- fused QKV GEMM: norm folded into B staging, A preloaded in regs ----
// Grid (128, 12) as round-15. LDS holds ONLY the normalized B tile (32 KB ->
// 5 blocks/CU vs 2 with A staged). Each wave's 8 A-fragments (its 16 weight
// rows) are register-preloaded from global BEFORE the barrier (L2-hot; can't
// be sunk into the loop).
__global__ __launch_bounds__(256) void qkv_gemm_kernel(
        const unsigned short* __restrict__ wqb,
        const unsigned short* __restrict__ wkvb,
        const float* __restrict__ xq, const float* __restrict__ xkv,
        const float* __restrict__ stats,
        const float* __restrict__ sq, const float* __restrict__ bq,
        const float* __restrict__ skv, const float* __restrict__ bkv,
        unsigned short* __restrict__ qbuf,
        unsigned short* __restrict__ kbuf,
        unsigned short* __restrict__ vbuf) {
    __shared__ unsigned short Bs[64 * 256];
    const int tid = threadIdx.x;
    const int l16 = tid & 15, g = (tid >> 4) & 3, w = tid >> 6;
    const int y = blockIdx.y;
    const bool isQ = y < 4;
    const int o0 = (isQ ? y : y - 4) * 64;
    const size_t prow0 = (size_t)blockIdx.x * 64;
    const int b = (int)(prow0 >> 10);
    const int pp = (int)(prow0 & 1023);

    const float* X  = (isQ ? xq : xkv) + (size_t)b * NC * HWSZ + pp;
    const float* st = stats + (isQ ? 0 : 512) + b * 64;
    const float* sc = isQ ? sq : skv;
    const float* bi = isQ ? bq : bkv;

    // A preload: 8 fragments for this wave's 16 weight rows (before barrier)
    const unsigned short* Asrc = (isQ ? wqb : wkvb)
                               + ((size_t)o0 + 16 * w + l16) * NC;
    bf16x8 af[8];
    #pragma unroll
    for (int kk = 0; kk < 8; ++kk)
        af[kk] = *(const bf16x8*)&Asrc[(kk * 4 + g) << 3];

    // B staging: fp32 X -> norm -> 4x4 reg transpose -> swizzled Bs
    const int cq = tid >> 4, pq = tid & 15;
    #pragma unroll
    for (int j = 0; j < 4; ++j) {
        int cb = cq * 4 + j * 64;
        int grp = cb >> 3;
        float mean = st[grp * 2], rstd = st[grp * 2 + 1];
        float mm[4][4];
        #pragma unroll
        for (int u = 0; u < 4; ++u) {
            int c = cb + u;
            float4 v = *(const float4*)&X[(size_t)c * HWSZ + pq * 4];
            float a = rstd * sc[c];
            float bbv = bi[c] - mean * a;
            mm[u][0] = v.x * a + bbv; mm[u][1] = v.y * a + bbv;
            mm[u][2] = v.z * a + bbv; mm[u][3] = v.w * a + bbv;
        }
        #pragma unroll
        for (int v2 = 0; v2 < 4; ++v2) {
            int row = pq * 4 + v2;
            int ds = row * 256 + ((((cb >> 3) ^ (row & 7))) << 3) + (cb & 7);
            uint2 s2;
            s2.x = pk2(mm[0][v2], mm[1][v2]);
            s2.y = pk2(mm[2][v2], mm[3][v2]);
            *(uint2*)&Bs[ds] = s2;
        }
    }
    __syncthreads();

    f32x4 acc[4] = {};
    const int asw = l16 & 7;
    #pragma unroll
    for (int kk = 0; kk < 8; ++kk) {
        const int koff = ((kk * 4 + g) ^ asw) << 3;
        #pragma unroll
        for (int j = 0; j < 4; ++j) {
            bf16x8 bfr = *(const bf16x8*)&Bs[(j * 16 + l16) * 256 + koff];
            acc[j] = __builtin_amdgcn_mfma_f32_16x16x32_bf16(af[kk], bfr, acc[j], 0, 0, 0);
        }
    }

    if (isQ) {
        int ob_ = o0 + 16 * w + 4 * g;
        int n = ob_ >> 5, d0 = ob_ & 31;
        unsigned short* dst = qbuf + ((size_t)(b * NHEAD + n) * HWSZ) * DHEAD + d0;
        #pragma unroll
        for (int j = 0; j < 4; ++j) {
            int p = pp + 16 * j + l16;
            uint2 st2;
            st2.x = pk2(acc[j][0], acc[j][1]);
            st2.y = pk2(acc[j][2], acc[j][3]);
            *(uint2*)&dst[(size_t)p * DHEAD] = st2;
        }
    } else {
        int n = o0 >> 6;
        int d0 = 16 * (w & 1) + 4 * g;
        if (w < 2) {   // K
            unsigned short* dst = kbuf + ((size_t)(b * NHEAD + n) * HWSZ) * DHEAD + d0;
            #pragma unroll
            for (int j = 0; j < 4; ++j) {
                int p = pp + 16 * j + l16;
                uint2 st2;
                st2.x = pk2(acc[j][0], acc[j][1]);
                st2.y = pk2(acc[j][2], acc[j][3]);
                *(uint2*)&dst[(size_t)p * DHEAD] = st2;
            }
        } else {
            // V -> [b][n][d][p'] sigma-permuted within each 32-key block
            unsigned short* dst = vbuf + ((size_t)(b * NHEAD + n) * DHEAD + d0) * HWSZ;
            #pragma unroll
            for (int j = 0; j < 4; ++j) {
                int slot = ((l16 >> 2) << 3) + ((j & 1) << 2) + (l16 & 3);
                int p = pp + 32 * (j >> 1) + slot;
                #pragma unroll
                for (int r = 0; r < 4; ++r)
                    dst[(size_t)r * HWSZ + p] = f2bf(acc[j][r]);
            }
        }
    }
}

// ---------------- out GEMM: A (obuf rows) preloaded in regs, B (Wout) staged ----
__global__ __launch_bounds__(256) void out_gemm_kernel(
        const unsigned short* __restrict__ Abase,
        const unsigned short* __restrict__ Bbase,
        const float* __restrict__ bias_out,
        const float* __restrict__ resid,
        float* __restrict__ out0) {
    __shared__ unsigned short Bs[64 * 256];
    const int tid = threadIdx.x;
    const int l16 = tid & 15, g = (tid >> 4) & 3, w = tid >> 6;
    const int o0 = blockIdx.y * 64;
    const size_t prow0 = (size_t)blockIdx.x * 64;

    // A preload: this wave's 16 obuf rows (before barrier)
    const unsigned short* Asrc = Abase + (prow0 + 16 * w + l16) * NC;
    bf16x8 af[8];
    #pragma unroll
    for (int kk = 0; kk < 8; ++kk)
        af[kk] = *(const bf16x8*)&Asrc[(kk * 4 + g) << 3];

    const unsigned short* Bsrc = Bbase + (size_t)o0 * NC;
    #pragma unroll
    for (int it = 0; it < 4; ++it) {
        int idx = tid + it * 256;
        int row = idx >> 4, seg = idx & 15;
        #pragma unroll
        for (int h = 0; h < 2; ++h) {
            int sg = seg * 2 + h;
            int ds = row * 256 + ((sg ^ (row & 7)) << 3);
            *(uint4*)&Bs[ds] = *(const uint4*)&Bsrc[(size_t)row * NC + sg * 8];
        }
    }
    __syncthreads();

    f32x4 acc[4] = {};
    const int asw = l16 & 7;
    #pragma unroll
    for (int kk = 0; kk < 8; ++kk) {
        const int koff = ((kk * 4 + g) ^ asw) << 3;
        #pragma unroll
        for (int j = 0; j < 4; ++j) {
            bf16x8 b = *(const bf16x8*)&Bs[(j * 16 + l16) * 256 + koff];
            acc[j] = __builtin_amdgcn_mfma_f32_16x16x32_bf16(af[kk], b, acc[j], 0, 0, 0);
        }
    }
    const int b = (int)(prow0 >> 10);
    const int pp = (int)(prow0 & 1023);
    int p_b = pp + 16 * w + 4 * g;
    #pragma unroll
    for (int j = 0; j < 4; ++j) {
        int o = o0 + 16 * j + l16;
        float bo = bias_out[o];
        size_t off = ((size_t)b * NC + o) * HWSZ + p_b;
        float4 rs = *(const float4*)&resid[off];
        float4 vst = make_float4(acc[j][0] + bo + rs.x, acc[j][1] + bo + rs.y,
                                 acc[j][2] + bo + rs.z, acc[j][3] + bo + rs.w);
        *(float4*)&out0[off] = vst;
    }
}

// ---------------- MFMA flash attention: async-LDS staging, max-free softmax ----
// (round-15 winner, unchanged)
__global__ __launch_bounds__(256) void attn_mfma_kernel(
        const unsigned short* __restrict__ qb,
        const unsigned short* __restrict__ kb,
        const unsigned short* __restrict__ vb,
        unsigned short* __restrict__ ob) {
    __shared__ unsigned short KV[3][4096];   // [buf][K: 0..2047 | V: 2048..4095]
    const int tid = threadIdx.x;
    const int w = tid >> 6, lane = tid & 63;
    const int l16 = lane & 15, g = lane >> 4;
    const int F = blockIdx.y * 16 + blockIdx.x;
    const int bn = (F & 7) * 8 + (F >> 7);
    const int qblk = (F >> 3) & 15;
    const int qp = qblk * 64 + w * 16 + l16;

    bf16x8 qf = *(const bf16x8*)(qb + ((size_t)bn * HWSZ + qp) * DHEAD + g * 8);

    const int kr = tid >> 2, ks = tid & 3;
    const unsigned short* ksrc = kb + (size_t)bn * HWSZ * DHEAD
                               + (size_t)kr * DHEAD + ((ks ^ (kr & 3)) << 3);
    const int vr = tid >> 3, vs = tid & 7;
    const unsigned short* vsrc = vb + (size_t)bn * DHEAD * HWSZ
                               + (size_t)vr * HWSZ + ((vs ^ (vr & 7)) << 3);
    unsigned short* lk = &KV[0][0] + w * 512;
    unsigned short* lv = &KV[0][2048] + w * 512;

#define STAGE(t) do {                                                        \
        int b3_ = (t) % 3; int ti_ = (t) & 15;                               \
        gload_lds16(ksrc + (size_t)ti_ * 64 * DHEAD, lk + b3_ * 4096);       \
        gload_lds16(vsrc + (size_t)ti_ * 64,         lv + b3_ * 4096);       \
    } while (0)

    f32x4 acc0 = {0.f, 0.f, 0.f, 0.f}, acc1 = {0.f, 0.f, 0.f, 0.f};
    f32x4 accl = {0.f, 0.f, 0.f, 0.f};
    const f32x4 z = {0.f, 0.f, 0.f, 0.f};

    const unsigned on2 = 0x3F803F80u;    // two bf16 1.0
    uint4 onev = make_uint4(on2, on2, on2, on2);
    bf16x8 ones;
    memcpy(&ones, &onev, sizeof(ones));

    const int ksw  = (g ^ (l16 & 3)) << 3;
    const int vsw0 = ((g)     ^ (l16 & 7)) << 3;
    const int vsw1 = ((4 + g) ^ (l16 & 7)) << 3;

    STAGE(0);
    STAGE(1);

    #pragma unroll
    for (int t = 0; t < 16; ++t) {
        const int cur = t % 3;
        asm volatile("s_waitcnt vmcnt(2)" ::: "memory");
        __builtin_amdgcn_s_barrier();
        STAGE(t + 2);

        const unsigned short* Kb = &KV[cur][0];
        const unsigned short* Vb = &KV[cur][2048];
        bf16x8 ka0 = *(const bf16x8*)&Kb[(l16)      * 32 + ksw];
        bf16x8 ka1 = *(const bf16x8*)&Kb[(16 + l16) * 32 + ksw];
        bf16x8 ka2 = *(const bf16x8*)&Kb[(32 + l16) * 32 + ksw];
        bf16x8 ka3 = *(const bf16x8*)&Kb[(48 + l16) * 32 + ksw];

        __builtin_amdgcn_s_setprio(1);
        f32x4 s0 = __builtin_amdgcn_mfma_f32_16x16x32_bf16(ka0, qf, z, 0, 0, 0);
        f32x4 s1 = __builtin_amdgcn_mfma_f32_16x16x32_bf16(ka1, qf, z, 0, 0, 0);
        f32x4 s2 = __builtin_amdgcn_mfma_f32_16x16x32_bf16(ka2, qf, z, 0, 0, 0);
        f32x4 s3 = __builtin_amdgcn_mfma_f32_16x16x32_bf16(ka3, qf, z, 0, 0, 0);
        __builtin_amdgcn_s_setprio(0);

        float p00 = ex2(s0[0]), p01 = ex2(s0[1]);
        float p02 = ex2(s0[2]), p03 = ex2(s0[3]);
        float p10 = ex2(s1[0]), p11 = ex2(s1[1]);
        float p12 = ex2(s1[2]), p13 = ex2(s1[3]);
        float p20 = ex2(s2[0]), p21 = ex2(s2[1]);
        float p22 = ex2(s2[2]), p23 = ex2(s2[3]);
        float p30 = ex2(s3[0]), p31 = ex2(s3[1]);
        float p32 = ex2(s3[2]), p33 = ex2(s3[3]);

        uint4 pwa, pwb;
        pwa.x = pk2t(p00, p01); pwa.y = pk2t(p02, p03);
        pwa.z = pk2t(p10, p11); pwa.w = pk2t(p12, p13);
        pwb.x = pk2t(p20, p21); pwb.y = pk2t(p22, p23);
        pwb.z = pk2t(p30, p31); pwb.w = pk2t(p32, p33);
        bf16x8 pf0, pf1;
        memcpy(&pf0, &pwa, sizeof(pf0));
        memcpy(&pf1, &pwb, sizeof(pf1));

        bf16x8 va0 = *(const bf16x8*)&Vb[(l16)      * 64 + vsw0];
        bf16x8 va1 = *(const bf16x8*)&Vb[(l16)      * 64 + vsw1];
        bf16x8 vb0 = *(const bf16x8*)&Vb[(16 + l16) * 64 + vsw0];
        bf16x8 vb1 = *(const bf16x8*)&Vb[(16 + l16) * 64 + vsw1];

        __builtin_amdgcn_s_setprio(1);
        acc0 = __builtin_amdgcn_mfma_f32_16x16x32_bf16(va0, pf0, acc0, 0, 0, 0);
        acc0 = __builtin_amdgcn_mfma_f32_16x16x32_bf16(va1, pf1, acc0, 0, 0, 0);
        acc1 = __builtin_amdgcn_mfma_f32_16x16x32_bf16(vb0, pf0, acc1, 0, 0, 0);
        acc1 = __builtin_amdgcn_mfma_f32_16x16x32_bf16(vb1, pf1, acc1, 0, 0, 0);
        accl = __builtin_amdgcn_mfma_f32_16x16x32_bf16(ones, pf0, accl, 0, 0, 0);
        accl = __builtin_amdgcn_mfma_f32_16x16x32_bf16(ones, pf1, accl, 0, 0, 0);
        __builtin_amdgcn_s_setprio(0);
    }
#undef STAGE

    float invl = 1.f / accl[0];

    const int b = bn >> 3, n = bn & 7;
    unsigned short* dst = ob + ((size_t)b * HWSZ + qp) * NC + n * DHEAD;
    uint2 st0, st1;
    st0.x = pk2(acc0[0] * invl, acc0[1] * invl);
    st0.y = pk2(acc0[2] * invl, acc0[3] * invl);
    st1.x = pk2(acc1[0] * invl, acc1[1] * invl);
    st1.y = pk2(acc1[2] * invl, acc1[3] * invl);
    *(uint2*)&dst[4 * g]      = st0;
    *(uint2*)&dst[16 + 4 * g] = st1;
}

extern "C" void kernel_launch(void* const* d_in, const int* in_sizes, int n_in,
                              void* d_out, int out_size, void* d_ws, size_t ws_size,
                              hipStream_t stream) {
    const float* input_q  = (const float*)d_in[0];
    const float* input_kv = (const float*)d_in[1];
    const float* gq_scale = (const float*)d_in[2];
    const float* gq_bias  = (const float*)d_in[3];
    const float* gkv_scale = (const float*)d_in[4];
    const float* gkv_bias  = (const float*)d_in[5];
    const float* Wq   = (const float*)d_in[6];
    const float* Wkv  = (const float*)d_in[7];
    const float* Wout = (const float*)d_in[8];
    const float* bout = (const float*)d_in[9];
    float* out = (float*)d_out;

    char* ws = (char*)d_ws;
    float* stats = (float*)ws;                                    // 8 KB
    unsigned short* wqb   = (unsigned short*)(ws + 16384);        // 128 KB
    unsigned short* wkvb  = (unsigned short*)(ws + 16384 + 131072);        // 256 KB
    unsigned short* woutb = (unsigned short*)(ws + 16384 + 131072 + 262144); // 128 KB
    const size_t MB = 1024 * 1024;
    unsigned short* qbuf = (unsigned short*)(ws + 1 * MB);   // 4 MB  [b][n][p][d]
    unsigned short* kbuf = (unsigned short*)(ws + 5 * MB);   // 4 MB  [b][n][p][d]
    unsigned short* vbuf = (unsigned short*)(ws + 9 * MB);   // 4 MB  [b][n][d][p'] sigma-permuted
    unsigned short* obuf = (unsigned short*)(ws + 13 * MB);  // 4 MB  [b][p][c]

    prep_kernel<<<640, 256, 0, stream>>>(input_q, input_kv, stats,
                                         Wq, Wkv, Wout, wqb, wkvb, woutb);
    qkv_gemm_kernel<<<dim3(128, 12), 256, 0, stream>>>(
        wqb, wkvb, input_q, input_kv, stats,
        gq_scale, gq_bias, gkv_scale, gkv_bias, qbuf, kbuf, vbuf);
    attn_mfma_kernel<<<dim3(16, 64), 256, 0, stream>>>(qbuf, kbuf, vbuf, obuf);
    out_gemm_kernel<<<dim3(128, 4), 256, 0, stream>>>(obuf, woutb, bout, input_q, out);
}

// Round 18
// 48.201 us; speedup vs baseline: 1.2836x; 1.0161x over previous
//
#include <hip/hip_runtime.h>
#include <hip/hip_bf16.h>
#include <math.h>
#include <string.h>

#define NB 8
#define NC 256
#define HWSZ 1024
#define NHEAD 8
#define DHEAD 32
#define NGRP 32
#define CPG 8
#define EPSV 1e-5f

typedef float f32x4 __attribute__((ext_vector_type(4)));
typedef short bf16x8 __attribute__((ext_vector_type(8)));

__device__ __forceinline__ unsigned pk2(float a, float b) {
    __hip_bfloat162 h = __float22bfloat162_rn(make_float2(a, b));
    unsigned r;
    memcpy(&r, &h, sizeof(r));
    return r;
}
// truncation pack (RTZ): P >= 0, rel error <= 0.4% downward
__device__ __forceinline__ unsigned pk2t(float a, float b) {
    unsigned ua = __float_as_uint(a), ub = __float_as_uint(b);
    return (ua >> 16) | (ub & 0xFFFF0000u);
}
__device__ __forceinline__ unsigned short f2bf(float x) {
    __hip_bfloat16 h = __float2bfloat16(x);
    unsigned short r;
    memcpy(&r, &h, sizeof(r));
    return r;
}
__device__ __forceinline__ float ex2(float x) { return __builtin_amdgcn_exp2f(x); }

// async global->LDS, 16B per lane; LDS dest = wave-uniform base + lane*16
__device__ __forceinline__ void gload_lds16(const void* g, void* l) {
    __builtin_amdgcn_global_load_lds(
        (const __attribute__((address_space(1))) unsigned int*)g,
        (__attribute__((address_space(3))) unsigned int*)l, 16, 0, 0);
}

// ---------------- prep ----------------
// blocks 0..511: GroupNorm stats for (which,b,g) + write NORMALIZED bf16 X in
//   MFMA-unit layout xn[which][b][g][p][8c] (reduction -> LDS broadcast ->
//   in-register 8c x 4p transpose; reads & writes fully coalesced).
// blocks 512..639: weight fp32->bf16 convert (Wq pre-scaled by 1/16*log2e).
__global__ void prep_kernel(const float* __restrict__ xq,
                            const float* __restrict__ xkv,
                            const float* __restrict__ gq_scale,
                            const float* __restrict__ gq_bias,
                            const float* __restrict__ gkv_scale,
                            const float* __restrict__ gkv_bias,
                            const float* __restrict__ Wq,
                            const float* __restrict__ Wkv,
                            const float* __restrict__ Wout,
                            unsigned short* __restrict__ xnq,
                            unsigned short* __restrict__ xnkv,
                            unsigned short* __restrict__ wqb,
                            unsigned short* __restrict__ wkvb,
                            unsigned short* __restrict__ woutb) {
    if (blockIdx.x < 512) {
        int idx = blockIdx.x;            // which*256 + b*32 + g
        int which = idx >> 8;
        int b = (idx >> 5) & 7;
        int g = idx & 31;
        const float* x = which ? xkv : xq;
        const float4* xb = (const float4*)(x + ((size_t)(b * NC + g * CPG)) * HWSZ);
        float s = 0.f, ss = 0.f;
        for (int i = threadIdx.x; i < (CPG * HWSZ) / 4; i += 256) {
            float4 v = xb[i];
            s += v.x + v.y + v.z + v.w;
            ss += v.x * v.x + v.y * v.y + v.z * v.z + v.w * v.w;
        }
        #pragma unroll
        for (int off = 32; off > 0; off >>= 1) {
            s += __shfl_down(s, off);
            ss += __shfl_down(ss, off);
        }
        __shared__ float red[10];
        int wid = threadIdx.x >> 6;
        if ((threadIdx.x & 63) == 0) { red[wid * 2] = s; red[wid * 2 + 1] = ss; }
        __syncthreads();
        if (threadIdx.x == 0) {
            float S = red[0] + red[2] + red[4] + red[6];
            float SS = red[1] + red[3] + red[5] + red[7];
            float mean = S * (1.f / (CPG * HWSZ));
            float var = SS * (1.f / (CPG * HWSZ)) - mean * mean;
            red[8] = mean;
            red[9] = rsqrtf(var + EPSV);
        }
        __syncthreads();
        const float mean = red[8], rstd = red[9];
        const float* scp = which ? gkv_scale : gq_scale;
        const float* bip = which ? gkv_bias : gq_bias;
        float a[8], bb[8];
        #pragma unroll
        for (int u = 0; u < 8; ++u) {
            int c = g * 8 + u;
            a[u] = rstd * scp[c];
            bb[u] = bip[c] - mean * a[u];
        }
        // normalized transpose write: thread t -> p rows 4t..4t+3
        const int p0 = threadIdx.x * 4;
        f32x4 rowv[8];
        #pragma unroll
        for (int u = 0; u < 8; ++u)
            rowv[u] = *(const f32x4*)&x[((size_t)(b * NC + g * 8 + u)) * HWSZ + p0];
        unsigned short* xt = (which ? xnkv : xnq)
                           + (((size_t)b * NGRP + g) * HWSZ) * 8;
        #pragma unroll
        for (int pi = 0; pi < 4; ++pi) {
            uint4 o;
            o.x = pk2(rowv[0][pi] * a[0] + bb[0], rowv[1][pi] * a[1] + bb[1]);
            o.y = pk2(rowv[2][pi] * a[2] + bb[2], rowv[3][pi] * a[3] + bb[3]);
            o.z = pk2(rowv[4][pi] * a[4] + bb[4], rowv[5][pi] * a[5] + bb[5]);
            o.w = pk2(rowv[6][pi] * a[6] + bb[6], rowv[7][pi] * a[7] + bb[7]);
            *(uint4*)&xt[(size_t)(p0 + pi) * 8] = o;
        }
    } else {
        int gid = (blockIdx.x - 512) * 256 + threadIdx.x;   // 32768 threads, 8 floats
        int i0 = gid * 8;
        const float* src; unsigned short* dst; int off; float sc = 1.f;
        if (i0 < 65536)       { src = Wq;   dst = wqb;   off = i0;          sc = 0.0625f * 1.44269504088896f; }
        else if (i0 < 196608) { src = Wkv;  dst = wkvb;  off = i0 - 65536; }
        else                  { src = Wout; dst = woutb; off = i0 - 196608; }
        float4 v0 = *(const float4*)&src[off];
        float4 v1 = *(const float4*)&src[off + 4];
        uint4 o;
        o.x = pk2(v0.x * sc, v0.y * sc); o.y = pk2(v0.z * sc, v0.w * sc);
        o.z = pk2(v1.x * sc, v1.y * sc); o.w = pk2(v1.z * sc, v1.w * sc);
        *(uint4*)&dst[off] = o;
    }
}

// ---------------- fused QKV GEMM: pure-copy B staging from pre-normalized xn ----
// Grid (128, 12). B tile staged by 8x {16B coalesced global load -> swizzled
// ds_write_b128}; A fragments register-preloaded before the barrier.
__global__ __launch_bounds__(256) void qkv_gemm_kernel(
        const unsigned short* __restrict__ wqb,
        const unsigned short* __restrict__ wkvb,
        const unsigned short* __restrict__ xnq,
        const unsigned short* __restrict__ xnkv,
        unsigned short* __restrict__ qbuf,
        unsigned short* __restrict__ kbuf,
        unsigned short* __restrict__ vbuf) {
    __shared__ unsigned short Bs[64 * 256];
    const int tid = threadIdx.x;
    const int l16 = tid & 15, g = (tid >> 4) & 3, w = tid >> 6;
    const int y = blockIdx.y;
    const bool isQ = y < 4;
    const int o0 = (isQ ? y : y - 4) * 64;
    const size_t prow0 = (size_t)blockIdx.x * 64;
    const int b = (int)(prow0 >> 10);
    const int pp = (int)(prow0 & 1023);

    // A preload: 8 fragments for this wave's 16 weight rows (before barrier)
    const unsigned short* Asrc = (isQ ? wqb : wkvb)
                               + ((size_t)o0 + 16 * w + l16) * NC;
    bf16x8 af[8];
    #pragma unroll
    for (int kk = 0; kk < 8; ++kk)
        af[kk] = *(const bf16x8*)&Asrc[(kk * 4 + g) << 3];

    // B staging: pure copy, 8 chunks/thread (coalesced along p)
    const unsigned short* Xn = (isQ ? xnq : xnkv) + (size_t)b * NGRP * HWSZ * 8;
    const int prow = tid & 63, gu0 = tid >> 6;
    #pragma unroll
    for (int i = 0; i < 8; ++i) {
        int gu = gu0 + i * 4;
        uint4 v = *(const uint4*)&Xn[((size_t)gu * HWSZ + pp + prow) * 8];
        int ds = prow * 256 + ((gu ^ (prow & 7)) << 3);
        *(uint4*)&Bs[ds] = v;
    }
    __syncthreads();

    f32x4 acc[4] = {};
    const int asw = l16 & 7;
    #pragma unroll
    for (int kk = 0; kk < 8; ++kk) {
        const int koff = ((kk * 4 + g) ^ asw) << 3;
        #pragma unroll
        for (int j = 0; j < 4; ++j) {
            bf16x8 bfr = *(const bf16x8*)&Bs[(j * 16 + l16) * 256 + koff];
            acc[j] = __builtin_amdgcn_mfma_f32_16x16x32_bf16(af[kk], bfr, acc[j], 0, 0, 0);
        }
    }

    if (isQ) {
        int ob_ = o0 + 16 * w + 4 * g;
        int n = ob_ >> 5, d0 = ob_ & 31;
        unsigned short* dst = qbuf + ((size_t)(b * NHEAD + n) * HWSZ) * DHEAD + d0;
        #pragma unroll
        for (int j = 0; j < 4; ++j) {
            int p = pp + 16 * j + l16;
            uint2 st2;
            st2.x = pk2(acc[j][0], acc[j][1]);
            st2.y = pk2(acc[j][2], acc[j][3]);
            *(uint2*)&dst[(size_t)p * DHEAD] = st2;
        }
    } else {
        int n = o0 >> 6;
        int d0 = 16 * (w & 1) + 4 * g;
        if (w < 2) {   // K
            unsigned short* dst = kbuf + ((size_t)(b * NHEAD + n) * HWSZ) * DHEAD + d0;
            #pragma unroll
            for (int j = 0; j < 4; ++j) {
                int p = pp + 16 * j + l16;
                uint2 st2;
                st2.x = pk2(acc[j][0], acc[j][1]);
                st2.y = pk2(acc[j][2], acc[j][3]);
                *(uint2*)&dst[(size_t)p * DHEAD] = st2;
            }
        } else {
            // V -> [b][n][d][p'] sigma-permuted within each 32-key block
            unsigned short* dst = vbuf + ((size_t)(b * NHEAD + n) * DHEAD + d0) * HWSZ;
            #pragma unroll
            for (int j = 0; j < 4; ++j) {
                int slot = ((l16 >> 2) << 3) + ((j & 1) << 2) + (l16 & 3);
                int p = pp + 32 * (j >> 1) + slot;
                #pragma unroll
                for (int r = 0; r < 4; ++r)
                    dst[(size_t)r * HWSZ + p] = f2bf(acc[j][r]);
            }
        }
    }
}

// ---------------- out GEMM: A (obuf rows) preloaded in regs, B (Wout) staged ----
__global__ __launch_bounds__(256) void out_gemm_kernel(
        const unsigned short* __restrict__ Abase,
        const unsigned short* __restrict__ Bbase,
        const float* __restrict__ bias_out,
        const float* __restrict__ resid,
        float* __restrict__ out0) {
    __shared__ unsigned short Bs[64 * 256];
    const int tid = threadIdx.x;
    const int l16 = tid & 15, g = (tid >> 4) & 3, w = tid >> 6;
    const int o0 = blockIdx.y * 64;
    const size_t prow0 = (size_t)blockIdx.x * 64;

    // A preload: this wave's 16 obuf rows (before barrier)
    const unsigned short* Asrc = Abase + (prow0 + 16 * w + l16) * NC;
    bf16x8 af[8];
    #pragma unroll
    for (int kk = 0; kk < 8; ++kk)
        af[kk] = *(const bf16x8*)&Asrc[(kk * 4 + g) << 3];

    const unsigned short* Bsrc = Bbase + (size_t)o0 * NC;
    #pragma unroll
    for (int it = 0; it < 4; ++it) {
        int idx = tid + it * 256;
        int row = idx >> 4, seg = idx & 15;
        #pragma unroll
        for (int h = 0; h < 2; ++h) {
            int sg = seg * 2 + h;
            int ds = row * 256 + ((sg ^ (row & 7)) << 3);
            *(uint4*)&Bs[ds] = *(const uint4*)&Bsrc[(size_t)row * NC + sg * 8];
        }
    }
    __syncthreads();

    f32x4 acc[4] = {};
    const int asw = l16 & 7;
    #pragma unroll
    for (int kk = 0; kk < 8; ++kk) {
        const int koff = ((kk * 4 + g) ^ asw) << 3;
        #pragma unroll
        for (int j = 0; j < 4; ++j) {
            bf16x8 b = *(const bf16x8*)&Bs[(j * 16 + l16) * 256 + koff];
            acc[j] = __builtin_amdgcn_mfma_f32_16x16x32_bf16(af[kk], b, acc[j], 0, 0, 0);
        }
    }
    const int b = (int)(prow0 >> 10);
    const int pp = (int)(prow0 & 1023);
    int p_b = pp + 16 * w + 4 * g;
    #pragma unroll
    for (int j = 0; j < 4; ++j) {
        int o = o0 + 16 * j + l16;
        float bo = bias_out[o];
        size_t off = ((size_t)b * NC + o) * HWSZ + p_b;
        float4 rs = *(const float4*)&resid[off];
        float4 vst = make_float4(acc[j][0] + bo + rs.x, acc[j][1] + bo + rs.y,
                                 acc[j][2] + bo + rs.z, acc[j][3] + bo + rs.w);
        *(float4*)&out0[off] = vst;
    }
}

// ---------------- MFMA flash attention: async-LDS staging, max-free softmax ----
// (round-15 winner, unchanged)
__global__ __launch_bounds__(256) void attn_mfma_kernel(
        const unsigned short* __restrict__ qb,
        const unsigned short* __restrict__ kb,
        const unsigned short* __restrict__ vb,
        unsigned short* __restrict__ ob) {
    __shared__ unsigned short KV[3][4096];   // [buf][K: 0..2047 | V: 2048..4095]
    const int tid = threadIdx.x;
    const int w = tid >> 6, lane = tid & 63;
    const int l16 = lane & 15, g = lane >> 4;
    const int F = blockIdx.y * 16 + blockIdx.x;
    const int bn = (F & 7) * 8 + (F >> 7);
    const int qblk = (F >> 3) & 15;
    const int qp = qblk * 64 + w * 16 + l16;

    bf16x8 qf = *(const bf16x8*)(qb + ((size_t)bn * HWSZ + qp) * DHEAD + g * 8);

    const int kr = tid >> 2, ks = tid & 3;
    const unsigned short* ksrc = kb + (size_t)bn * HWSZ * DHEAD
                               + (size_t)kr * DHEAD + ((ks ^ (kr & 3)) << 3);
    const int vr = tid >> 3, vs = tid & 7;
    const unsigned short* vsrc = vb + (size_t)bn * DHEAD * HWSZ
                               + (size_t)vr * HWSZ + ((vs ^ (vr & 7)) << 3);
    unsigned short* lk = &KV[0][0] + w * 512;
    unsigned short* lv = &KV[0][2048] + w * 512;

#define STAGE(t) do {                                                        \
        int b3_ = (t) % 3; int ti_ = (t) & 15;                               \
        gload_lds16(ksrc + (size_t)ti_ * 64 * DHEAD, lk + b3_ * 4096);       \
        gload_lds16(vsrc + (size_t)ti_ * 64,         lv + b3_ * 4096);       \
    } while (0)

    f32x4 acc0 = {0.f, 0.f, 0.f, 0.f}, acc1 = {0.f, 0.f, 0.f, 0.f};
    f32x4 accl = {0.f, 0.f, 0.f, 0.f};
    const f32x4 z = {0.f, 0.f, 0.f, 0.f};

    const unsigned on2 = 0x3F803F80u;    // two bf16 1.0
    uint4 onev = make_uint4(on2, on2, on2, on2);
    bf16x8 ones;
    memcpy(&ones, &onev, sizeof(ones));

    const int ksw  = (g ^ (l16 & 3)) << 3;
    const int vsw0 = ((g)     ^ (l16 & 7)) << 3;
    const int vsw1 = ((4 + g) ^ (l16 & 7)) << 3;

    STAGE(0);
    STAGE(1);

    #pragma unroll
    for (int t = 0; t < 16; ++t) {
        const int cur = t % 3;
        asm volatile("s_waitcnt vmcnt(2)" ::: "memory");
        __builtin_amdgcn_s_barrier();
        STAGE(t + 2);

        const unsigned short* Kb = &KV[cur][0];
        const unsigned short* Vb = &KV[cur][2048];
        bf16x8 ka0 = *(const bf16x8*)&Kb[(l16)      * 32 + ksw];
        bf16x8 ka1 = *(const bf16x8*)&Kb[(16 + l16) * 32 + ksw];
        bf16x8 ka2 = *(const bf16x8*)&Kb[(32 + l16) * 32 + ksw];
        bf16x8 ka3 = *(const bf16x8*)&Kb[(48 + l16) * 32 + ksw];

        __builtin_amdgcn_s_setprio(1);
        f32x4 s0 = __builtin_amdgcn_mfma_f32_16x16x32_bf16(ka0, qf, z, 0, 0, 0);
        f32x4 s1 = __builtin_amdgcn_mfma_f32_16x16x32_bf16(ka1, qf, z, 0, 0, 0);
        f32x4 s2 = __builtin_amdgcn_mfma_f32_16x16x32_bf16(ka2, qf, z, 0, 0, 0);
        f32x4 s3 = __builtin_amdgcn_mfma_f32_16x16x32_bf16(ka3, qf, z, 0, 0, 0);
        __builtin_amdgcn_s_setprio(0);

        float p00 = ex2(s0[0]), p01 = ex2(s0[1]);
        float p02 = ex2(s0[2]), p03 = ex2(s0[3]);
        float p10 = ex2(s1[0]), p11 = ex2(s1[1]);
        float p12 = ex2(s1[2]), p13 = ex2(s1[3]);
        float p20 = ex2(s2[0]), p21 = ex2(s2[1]);
        float p22 = ex2(s2[2]), p23 = ex2(s2[3]);
        float p30 = ex2(s3[0]), p31 = ex2(s3[1]);
        float p32 = ex2(s3[2]), p33 = ex2(s3[3]);

        uint4 pwa, pwb;
        pwa.x = pk2t(p00, p01); pwa.y = pk2t(p02, p03);
        pwa.z = pk2t(p10, p11); pwa.w = pk2t(p12, p13);
        pwb.x = pk2t(p20, p21); pwb.y = pk2t(p22, p23);
        pwb.z = pk2t(p30, p31); pwb.w = pk2t(p32, p33);
        bf16x8 pf0, pf1;
        memcpy(&pf0, &pwa, sizeof(pf0));
        memcpy(&pf1, &pwb, sizeof(pf1));

        bf16x8 va0 = *(const bf16x8*)&Vb[(l16)      * 64 + vsw0];
        bf16x8 va1 = *(const bf16x8*)&Vb[(l16)      * 64 + vsw1];
        bf16x8 vb0 = *(const bf16x8*)&Vb[(16 + l16) * 64 + vsw0];
        bf16x8 vb1 = *(const bf16x8*)&Vb[(16 + l16) * 64 + vsw1];

        __builtin_amdgcn_s_setprio(1);
        acc0 = __builtin_amdgcn_mfma_f32_16x16x32_bf16(va0, pf0, acc0, 0, 0, 0);
        acc0 = __builtin_amdgcn_mfma_f32_16x16x32_bf16(va1, pf1, acc0, 0, 0, 0);
        acc1 = __builtin_amdgcn_mfma_f32_16x16x32_bf16(vb0, pf0, acc1, 0, 0, 0);
        acc1 = __builtin_amdgcn_mfma_f32_16x16x32_bf16(vb1, pf1, acc1, 0, 0, 0);
        accl = __builtin_amdgcn_mfma_f32_16x16x32_bf16(ones, pf0, accl, 0, 0, 0);
        accl = __builtin_amdgcn_mfma_f32_16x16x32_bf16(ones, pf1, accl, 0, 0, 0);
        __builtin_amdgcn_s_setprio(0);
    }
#undef STAGE

    float invl = 1.f / accl[0];

    const int b = bn >> 3, n = bn & 7;
    unsigned short* dst = ob + ((size_t)b * HWSZ + qp) * NC + n * DHEAD;
    uint2 st0, st1;
    st0.x = pk2(acc0[0] * invl, acc0[1] * invl);
    st0.y = pk2(acc0[2] * invl, acc0[3] * invl);
    st1.x = pk2(acc1[0] * invl, acc1[1] * invl);
    st1.y = pk2(acc1[2] * invl, acc1[3] * invl);
    *(uint2*)&dst[4 * g]      = st0;
    *(uint2*)&dst[16 + 4 * g] = st1;
}

extern "C" void kernel_launch(void* const* d_in, const int* in_sizes, int n_in,
                              void* d_out, int out_size, void* d_ws, size_t ws_size,
                              hipStream_t stream) {
    const float* input_q  = (const float*)d_in[0];
    const float* input_kv = (const float*)d_in[1];
    const float* gq_scale = (const float*)d_in[2];
    const float* gq_bias  = (const float*)d_in[3];
    const float* gkv_scale = (const float*)d_in[4];
    const float* gkv_bias  = (const float*)d_in[5];
    const float* Wq   = (const float*)d_in[6];
    const float* Wkv  = (const float*)d_in[7];
    const float* Wout = (const float*)d_in[8];
    const float* bout = (const float*)d_in[9];
    float* out = (float*)d_out;

    char* ws = (char*)d_ws;
    unsigned short* wqb   = (unsigned short*)(ws + 16384);        // 128 KB
    unsigned short* wkvb  = (unsigned short*)(ws + 16384 + 131072);        // 256 KB
    unsigned short* woutb = (unsigned short*)(ws + 16384 + 131072 + 262144); // 128 KB
    const size_t MB = 1024 * 1024;
    unsigned short* xnq  = (unsigned short*)(ws + 1 * MB);   // 4 MB  [b][g][p][8c]
    unsigned short* xnkv = (unsigned short*)(ws + 5 * MB);   // 4 MB  [b][g][p][8c]
    unsigned short* qbuf = (unsigned short*)(ws + 9 * MB);   // 4 MB  [b][n][p][d]
    unsigned short* kbuf = (unsigned short*)(ws + 13 * MB);  // 4 MB  [b][n][p][d]
    unsigned short* vbuf = (unsigned short*)(ws + 17 * MB);  // 4 MB  [b][n][d][p'] sigma-permuted
    unsigned short* obuf = (unsigned short*)(ws + 21 * MB);  // 4 MB  [b][p][c]

    prep_kernel<<<640, 256, 0, stream>>>(
        input_q, input_kv, gq_scale, gq_bias, gkv_scale, gkv_bias,
        Wq, Wkv, Wout, xnq, xnkv, wqb, wkvb, woutb);
    qkv_gemm_kernel<<<dim3(128, 12), 256, 0, stream>>>(
        wqb, wkvb, xnq, xnkv, qbuf, kbuf, vbuf);
    attn_mfma_kernel<<<dim3(16, 64), 256, 0, stream>>>(qbuf, kbuf, vbuf, obuf);
    out_gemm_kernel<<<dim3(128, 4), 256, 0, stream>>>(obuf, woutb, bout, input_q, out);
}